// Round 2
// baseline (105.156 us; speedup 1.0000x reference)
//
#include <hip/hip_runtime.h>

#define HD 64      // HIDDEN_DIM
#define VC 128     // VOCAB_SIZE
#define NS 64      // NUM_SLOTS
#define NB 256     // B
#define SL 4096    // L

__device__ __forceinline__ float wsum(float x) {
#pragma unroll
  for (int o = 32; o > 0; o >>= 1) x += __shfl_xor(x, o, 64);
  return x;
}
__device__ __forceinline__ float wmax(float x) {
#pragma unroll
  for (int o = 32; o > 0; o >>= 1) x = fmaxf(x, __shfl_xor(x, o, 64));
  return x;
}

// Kernel 1: per-vocab tables.
// HN[v][h]  = layer_norm(e + FFN(e))           (128 x 64, f32)
// WSM[v][n] = softmax(HN[v] @ gate_w + gate_b) (128 x 64, f32)
__global__ __launch_bounds__(128) void build_tables(
    const float* __restrict__ embed, const float* __restrict__ w1, const float* __restrict__ b1,
    const float* __restrict__ w2, const float* __restrict__ b2,
    const float* __restrict__ ln_g, const float* __restrict__ ln_b,
    const float* __restrict__ gate_w, const float* __restrict__ gate_b,
    float* __restrict__ HN, float* __restrict__ WSM)
{
  const int v = blockIdx.x, t = threadIdx.x;
  __shared__ float s_e[HD], s_f1[2 * HD], s_hn[HD];

  if (t < HD) s_e[t] = embed[v * HD + t];
  __syncthreads();

  // ff1 = relu(e @ w1 + b1), one output per thread (128 outputs)
  float acc = b1[t];
  for (int h = 0; h < HD; ++h)
    acc = fmaf(s_e[h], w1[h * 2 * HD + t], acc);
  s_f1[t] = fmaxf(acc, 0.f);
  __syncthreads();

  // ff2 + residual + layernorm (wave 0 only: threads 0..63 = one full wave)
  if (t < HD) {
    float a2 = b2[t];
    for (int j = 0; j < 2 * HD; ++j)
      a2 = fmaf(s_f1[j], w2[j * HD + t], a2);
    float x = s_e[t] + a2;
    float mu = wsum(x) * (1.f / 64.f);
    float d = x - mu;
    float var = wsum(d * d) * (1.f / 64.f);
    float hn = d * rsqrtf(var + 1e-5f) * ln_g[t] + ln_b[t];
    s_hn[t] = hn;
    HN[v * HD + t] = hn;
  }
  __syncthreads();

  // gate softmax over slots (wave 0)
  if (t < NS) {
    float g = gate_b[t];
    for (int h = 0; h < HD; ++h)
      g = fmaf(s_hn[h], gate_w[h * NS + t], g);
    float m = wmax(g);
    float e = expf(g - m);
    float s = wsum(e);
    WSM[v * NS + t] = e / s;
  }
}

// Kernel 2: one block per batch.
// cnt[v] = histogram(seq[b, :L-1]); A = (cnt*WSM)^T @ HN; keys = slot_keys + A;
// sim = l2norm(keys) . l2norm(q); attn = softmax(sim); ctx = attn @ keys;
// out = ctx @ out_w + out_b
__global__ __launch_bounds__(256) void batch_kernel(
    const int* __restrict__ seq, const float* __restrict__ HN, const float* __restrict__ WSM,
    const float* __restrict__ slot_keys, const float* __restrict__ out_w,
    const float* __restrict__ out_b, float* __restrict__ out)
{
  const int b = blockIdx.x, t = threadIdx.x;
  const int lane = t & 63, wave = t >> 6;

  __shared__ int s_cnt[VC];
  __shared__ int s_qtok;
  __align__(16) __shared__ float s_hn[64 * HD];   // half-vocab staging
  __align__(16) __shared__ float s_wsm[64 * NS];  // cnt-scaled, half-vocab
  __align__(16) __shared__ float s_keys[NS * HD];
  __shared__ float s_q[HD], s_sim[NS], s_attn[NS], s_ctx[HD];

  if (t < VC) s_cnt[t] = 0;
  __syncthreads();

  const int* sb = seq + b * SL;
  for (int i = t; i < SL - 1; i += 256) atomicAdd(&s_cnt[sb[i]], 1);
  if (t == 0) s_qtok = sb[SL - 1];
  __syncthreads();

  if (t < HD) s_q[t] = HN[s_qtok * HD + t];

  // per-thread 4x4 tile of A: n in [n0,n0+4), h in [h0,h0+4)
  const int n0 = (t >> 4) << 2;
  const int h0 = (t & 15) << 2;
  float accv[4][4];
#pragma unroll
  for (int r = 0; r < 4; ++r)
#pragma unroll
    for (int c = 0; c < 4; ++c)
      accv[r][c] = slot_keys[(n0 + r) * HD + h0 + c];

  // two passes of 64 vocab ids each to keep static LDS < 64 KB
  for (int p = 0; p < 2; ++p) {
    for (int i = t; i < 64 * HD; i += 256) {
      int v = (i >> 6) + (p << 6);
      s_hn[i] = HN[p * 64 * HD + i];
      s_wsm[i] = (float)s_cnt[v] * WSM[p * 64 * NS + i];
    }
    __syncthreads();
#pragma unroll 4
    for (int v = 0; v < 64; ++v) {
      const float4 hv = *(const float4*)&s_hn[v * HD + h0];   // lane-stride-1: conflict-free
      const float4 wv = *(const float4*)&s_wsm[v * NS + n0];  // wave-quasi-uniform: broadcast
      accv[0][0] = fmaf(wv.x, hv.x, accv[0][0]);
      accv[0][1] = fmaf(wv.x, hv.y, accv[0][1]);
      accv[0][2] = fmaf(wv.x, hv.z, accv[0][2]);
      accv[0][3] = fmaf(wv.x, hv.w, accv[0][3]);
      accv[1][0] = fmaf(wv.y, hv.x, accv[1][0]);
      accv[1][1] = fmaf(wv.y, hv.y, accv[1][1]);
      accv[1][2] = fmaf(wv.y, hv.z, accv[1][2]);
      accv[1][3] = fmaf(wv.y, hv.w, accv[1][3]);
      accv[2][0] = fmaf(wv.z, hv.x, accv[2][0]);
      accv[2][1] = fmaf(wv.z, hv.y, accv[2][1]);
      accv[2][2] = fmaf(wv.z, hv.z, accv[2][2]);
      accv[2][3] = fmaf(wv.z, hv.w, accv[2][3]);
      accv[3][0] = fmaf(wv.w, hv.x, accv[3][0]);
      accv[3][1] = fmaf(wv.w, hv.y, accv[3][1]);
      accv[3][2] = fmaf(wv.w, hv.z, accv[3][2]);
      accv[3][3] = fmaf(wv.w, hv.w, accv[3][3]);
    }
    __syncthreads();  // before next pass overwrites s_hn/s_wsm
  }

#pragma unroll
  for (int r = 0; r < 4; ++r) {
    float4 st;
    st.x = accv[r][0]; st.y = accv[r][1]; st.z = accv[r][2]; st.w = accv[r][3];
    *(float4*)&s_keys[(n0 + r) * HD + h0] = st;
  }
  __syncthreads();

  // sim[n] = (k_n . q) / (max(|k_n|,eps) * max(|q|,eps)); each wave owns 16 rows
  const float qv = s_q[lane];
  const float qn = fmaxf(sqrtf(wsum(qv * qv)), 1e-12f);
  for (int r = 0; r < 16; ++r) {
    const int n = wave * 16 + r;
    const float kv = s_keys[n * HD + lane];
    const float kk = wsum(kv * kv);
    const float kq = wsum(kv * qv);
    if (lane == 0) s_sim[n] = kq / (fmaxf(sqrtf(kk), 1e-12f) * qn);
  }
  __syncthreads();

  if (wave == 0) {
    float sv = s_sim[lane];
    float m = wmax(sv);
    float e = expf(sv - m);
    float ssum = wsum(e);
    s_attn[lane] = e / ssum;
  }
  __syncthreads();

  if (wave == 0) {
    float c = 0.f;
    for (int n = 0; n < NS; ++n) c = fmaf(s_attn[n], s_keys[n * HD + lane], c);
    s_ctx[lane] = c;
  }
  __syncthreads();

  if (t < VC) {
    float o = out_b[t];
    for (int h = 0; h < HD; ++h)
      o = fmaf(s_ctx[h], out_w[h * VC + t], o);
    out[b * VC + t] = o;
  }
}

extern "C" void kernel_launch(void* const* d_in, const int* in_sizes, int n_in,
                              void* d_out, int out_size, void* d_ws, size_t ws_size,
                              hipStream_t stream) {
  const int* seq         = (const int*)d_in[0];
  const float* embed_w   = (const float*)d_in[1];
  const float* w1        = (const float*)d_in[2];
  const float* b1        = (const float*)d_in[3];
  const float* w2        = (const float*)d_in[4];
  const float* b2        = (const float*)d_in[5];
  const float* ln_g      = (const float*)d_in[6];
  const float* ln_b      = (const float*)d_in[7];
  const float* slot_keys = (const float*)d_in[8];
  // d_in[9] = slot_vals: unused (reference sets vals = keys)
  const float* gate_w    = (const float*)d_in[10];
  const float* gate_b    = (const float*)d_in[11];
  const float* out_w     = (const float*)d_in[12];
  const float* out_b     = (const float*)d_in[13];
  float* out = (float*)d_out;

  float* HN  = (float*)d_ws;       // 128*64 f32
  float* WSM = HN + VC * HD;       // 128*64 f32

  build_tables<<<VC, 128, 0, stream>>>(embed_w, w1, b1, w2, b2, ln_g, ln_b,
                                       gate_w, gate_b, HN, WSM);
  batch_kernel<<<NB, 256, 0, stream>>>(seq, HN, WSM, slot_keys, out_w, out_b, out);
}

// Round 3
// 103.430 us; speedup vs baseline: 1.0167x; 1.0167x over previous
//
#include <hip/hip_runtime.h>

#define HD 64      // HIDDEN_DIM
#define VC 128     // VOCAB_SIZE
#define NS 64      // NUM_SLOTS
#define NB 256     // B
#define SL 4096    // L

__device__ __forceinline__ float wsum(float x) {
#pragma unroll
  for (int o = 32; o > 0; o >>= 1) x += __shfl_xor(x, o, 64);
  return x;
}
__device__ __forceinline__ float wmax(float x) {
#pragma unroll
  for (int o = 32; o > 0; o >>= 1) x = fmaxf(x, __shfl_xor(x, o, 64));
  return x;
}

// Kernel 1: per-vocab tables.
// HN[v][h]  = layer_norm(e + FFN(e))           (128 x 64, f32)
// WSM[v][n] = softmax(HN[v] @ gate_w + gate_b) (128 x 64, f32)
__global__ __launch_bounds__(128) void build_tables(
    const float* __restrict__ embed, const float* __restrict__ w1, const float* __restrict__ b1,
    const float* __restrict__ w2, const float* __restrict__ b2,
    const float* __restrict__ ln_g, const float* __restrict__ ln_b,
    const float* __restrict__ gate_w, const float* __restrict__ gate_b,
    float* __restrict__ HN, float* __restrict__ WSM)
{
  const int v = blockIdx.x, t = threadIdx.x;
  __shared__ float s_e[HD], s_f1[2 * HD], s_hn[HD];

  if (t < HD) s_e[t] = embed[v * HD + t];
  __syncthreads();

  // ff1 = relu(e @ w1 + b1), one output per thread (128 outputs)
  float acc = b1[t];
#pragma unroll 8
  for (int h = 0; h < HD; ++h)
    acc = fmaf(s_e[h], w1[h * 2 * HD + t], acc);
  s_f1[t] = fmaxf(acc, 0.f);
  __syncthreads();

  // ff2 + residual + layernorm (wave 0 only: threads 0..63 = one full wave)
  if (t < HD) {
    float a2 = b2[t];
#pragma unroll 8
    for (int j = 0; j < 2 * HD; ++j)
      a2 = fmaf(s_f1[j], w2[j * HD + t], a2);
    float x = s_e[t] + a2;
    float mu = wsum(x) * (1.f / 64.f);
    float d = x - mu;
    float var = wsum(d * d) * (1.f / 64.f);
    float hn = d * rsqrtf(var + 1e-5f) * ln_g[t] + ln_b[t];
    s_hn[t] = hn;
    HN[v * HD + t] = hn;
  }
  __syncthreads();

  // gate softmax over slots (wave 0)
  if (t < NS) {
    float g = gate_b[t];
#pragma unroll 8
    for (int h = 0; h < HD; ++h)
      g = fmaf(s_hn[h], gate_w[h * NS + t], g);
    float m = wmax(g);
    float e = expf(g - m);
    float s = wsum(e);
    WSM[v * NS + t] = e / s;
  }
}

// Kernel 2: one block per batch, 512 threads (8 waves).
// cnt[v] = histogram(seq[b, :L-1]); A = (cnt*WSM)^T @ HN; keys = slot_keys + A;
// sim = l2norm(keys) . l2norm(q); attn = softmax(sim); ctx = attn @ keys;
// out = ctx @ out_w + out_b
// Waves 0-3 accumulate vocab [0,64), waves 4-7 vocab [64,128); combined via s_keys.
__global__ __launch_bounds__(512) void batch_kernel(
    const int* __restrict__ seq, const float* __restrict__ HN, const float* __restrict__ WSM,
    const float* __restrict__ slot_keys, const float* __restrict__ out_w,
    const float* __restrict__ out_b, float* __restrict__ out)
{
  const int b = blockIdx.x, t = threadIdx.x;
  const int lane = t & 63, wave = t >> 6;

  __shared__ int s_cnt[VC];
  __shared__ int s_qtok;
  __align__(16) __shared__ float s_hn[VC * HD];    // 32 KB: full-vocab HN
  __align__(16) __shared__ float s_wsm[VC * NS];   // 32 KB: cnt-scaled WSM
  __align__(16) __shared__ float s_keys[NS * HD];  // 16 KB
  __shared__ float s_part[8 * HD];                 // ctx partials per wave
  __shared__ float s_q[HD], s_sim[NS], s_attn[NS], s_ctx[HD];

  if (t < VC) s_cnt[t] = 0;
  __syncthreads();

  // Phase 1: histogram (atomics) overlapped with HN staging (float4)
  const int* sb = seq + b * SL;
  for (int i = t; i < SL - 1; i += 512) atomicAdd(&s_cnt[sb[i]], 1);
  if (t == 0) s_qtok = sb[SL - 1];
#pragma unroll
  for (int i4 = t; i4 < VC * HD / 4; i4 += 512)
    ((float4*)s_hn)[i4] = ((const float4*)HN)[i4];
  __syncthreads();

  // Phase 2: cnt-scaled WSM staging (float4); q fetch from LDS
  if (t < HD) s_q[t] = s_hn[s_qtok * HD + t];
#pragma unroll
  for (int i4 = t; i4 < VC * NS / 4; i4 += 512) {
    float4 wv = ((const float4*)WSM)[i4];
    const float c = (float)s_cnt[i4 >> 4];  // 16 float4 per 64-float row
    wv.x *= c; wv.y *= c; wv.z *= c; wv.w *= c;
    ((float4*)s_wsm)[i4] = wv;
  }
  __syncthreads();

  // Phase 3: A += (cnt*WSM)^T @ HN over this half's 64 vocab ids.
  // per-thread 4x4 tile: n in [n0,n0+4), h in [h0,h0+4)
  const int tid = t & 255;
  const int half = t >> 8;  // 0: vocab [0,64), 1: vocab [64,128)
  const int n0 = (tid >> 4) << 2;
  const int h0 = (tid & 15) << 2;
  const float* hbase = s_hn + half * 64 * HD;
  const float* wbase = s_wsm + half * 64 * NS;

  float accv[4][4];
  if (half == 0) {
#pragma unroll
    for (int r = 0; r < 4; ++r) {
      const float4 sk = *(const float4*)&slot_keys[(n0 + r) * HD + h0];
      accv[r][0] = sk.x; accv[r][1] = sk.y; accv[r][2] = sk.z; accv[r][3] = sk.w;
    }
  } else {
#pragma unroll
    for (int r = 0; r < 4; ++r)
#pragma unroll
      for (int c = 0; c < 4; ++c) accv[r][c] = 0.f;
  }

#pragma unroll 4
  for (int v = 0; v < 64; ++v) {
    const float4 hv = *(const float4*)&hbase[v * HD + h0];  // 16 distinct addrs/wave
    const float4 wv = *(const float4*)&wbase[v * NS + n0];  // 4 distinct addrs/wave (broadcast)
    accv[0][0] = fmaf(wv.x, hv.x, accv[0][0]);
    accv[0][1] = fmaf(wv.x, hv.y, accv[0][1]);
    accv[0][2] = fmaf(wv.x, hv.z, accv[0][2]);
    accv[0][3] = fmaf(wv.x, hv.w, accv[0][3]);
    accv[1][0] = fmaf(wv.y, hv.x, accv[1][0]);
    accv[1][1] = fmaf(wv.y, hv.y, accv[1][1]);
    accv[1][2] = fmaf(wv.y, hv.z, accv[1][2]);
    accv[1][3] = fmaf(wv.y, hv.w, accv[1][3]);
    accv[2][0] = fmaf(wv.z, hv.x, accv[2][0]);
    accv[2][1] = fmaf(wv.z, hv.y, accv[2][1]);
    accv[2][2] = fmaf(wv.z, hv.z, accv[2][2]);
    accv[2][3] = fmaf(wv.z, hv.w, accv[2][3]);
    accv[3][0] = fmaf(wv.w, hv.x, accv[3][0]);
    accv[3][1] = fmaf(wv.w, hv.y, accv[3][1]);
    accv[3][2] = fmaf(wv.w, hv.z, accv[3][2]);
    accv[3][3] = fmaf(wv.w, hv.w, accv[3][3]);
  }
  __syncthreads();

  // Combine halves into s_keys
  if (half == 1) {
#pragma unroll
    for (int r = 0; r < 4; ++r) {
      float4 st; st.x = accv[r][0]; st.y = accv[r][1]; st.z = accv[r][2]; st.w = accv[r][3];
      *(float4*)&s_keys[(n0 + r) * HD + h0] = st;
    }
  }
  __syncthreads();
  if (half == 0) {
#pragma unroll
    for (int r = 0; r < 4; ++r) {
      float4 p = *(const float4*)&s_keys[(n0 + r) * HD + h0];
      p.x += accv[r][0]; p.y += accv[r][1]; p.z += accv[r][2]; p.w += accv[r][3];
      *(float4*)&s_keys[(n0 + r) * HD + h0] = p;
    }
  }
  __syncthreads();

  // Phase 4: sim[n] — each of 8 waves owns 8 slot rows
  const float qv = s_q[lane];
  const float qn = fmaxf(sqrtf(wsum(qv * qv)), 1e-12f);
#pragma unroll
  for (int r = 0; r < 8; ++r) {
    const int n = wave * 8 + r;
    const float kv = s_keys[n * HD + lane];
    const float kk = wsum(kv * kv);
    const float kq = wsum(kv * qv);
    if (lane == 0) s_sim[n] = kq / (fmaxf(sqrtf(kk), 1e-12f) * qn);
  }
  __syncthreads();

  // Phase 5: softmax over 64 slots (wave 0)
  if (wave == 0) {
    float sv = s_sim[lane];
    float m = wmax(sv);
    float e = expf(sv - m);
    float ssum = wsum(e);
    s_attn[lane] = e / ssum;
  }
  __syncthreads();

  // Phase 6: ctx partials — wave w covers slots [8w, 8w+8), lane = h
  {
    float c = 0.f;
#pragma unroll
    for (int r = 0; r < 8; ++r) {
      const int n = wave * 8 + r;
      c = fmaf(s_attn[n], s_keys[n * HD + lane], c);
    }
    s_part[wave * HD + lane] = c;
  }
  __syncthreads();
  if (wave == 0) {
    float c = 0.f;
#pragma unroll
    for (int w = 0; w < 8; ++w) c += s_part[w * HD + lane];
    s_ctx[lane] = c;
  }
  __syncthreads();

  // Phase 7: out = ctx @ out_w + out_b (threads 0..127, coalesced out_w)
  if (t < VC) {
    float o = out_b[t];
#pragma unroll 8
    for (int h = 0; h < HD; ++h)
      o = fmaf(s_ctx[h], out_w[h * VC + t], o);
    out[b * VC + t] = o;
  }
}

extern "C" void kernel_launch(void* const* d_in, const int* in_sizes, int n_in,
                              void* d_out, int out_size, void* d_ws, size_t ws_size,
                              hipStream_t stream) {
  const int* seq         = (const int*)d_in[0];
  const float* embed_w   = (const float*)d_in[1];
  const float* w1        = (const float*)d_in[2];
  const float* b1        = (const float*)d_in[3];
  const float* w2        = (const float*)d_in[4];
  const float* b2        = (const float*)d_in[5];
  const float* ln_g      = (const float*)d_in[6];
  const float* ln_b      = (const float*)d_in[7];
  const float* slot_keys = (const float*)d_in[8];
  // d_in[9] = slot_vals: unused (reference sets vals = keys)
  const float* gate_w    = (const float*)d_in[10];
  const float* gate_b    = (const float*)d_in[11];
  const float* out_w     = (const float*)d_in[12];
  const float* out_b     = (const float*)d_in[13];
  float* out = (float*)d_out;

  float* HN  = (float*)d_ws;       // 128*64 f32
  float* WSM = HN + VC * HD;       // 128*64 f32

  build_tables<<<VC, 128, 0, stream>>>(embed_w, w1, b1, w2, b2, ln_g, ln_b,
                                       gate_w, gate_b, HN, WSM);
  batch_kernel<<<NB, 512, 0, stream>>>(seq, HN, WSM, slot_keys, out_w, out_b, out);
}